// Round 1
// 205.085 us; speedup vs baseline: 1.0158x; 1.0158x over previous
//
#include <hip/hip_runtime.h>

#define B_ 64
#define N_ 8192

using short8 = __attribute__((ext_vector_type(8))) short;  // 8 bf16 (4 VGPRs)
using f32x4  = __attribute__((ext_vector_type(4))) float;

#define MFMA16(a, b, c) __builtin_amdgcn_mfma_f32_16x16x32_bf16((a), (b), (c), 0, 0, 0)

// round-half-up bf16: same 2^-9 max-rel-err bound as RNE, 2 VALU instrs
__device__ inline unsigned short f2bf(float f) {
  union { float f; unsigned int u; } v; v.f = f;
  return (unsigned short)((v.u + 0x8000u) >> 16);
}
__device__ inline float bf2f(unsigned int hi16_in_low) {
  union { unsigned int u; float f; } v; v.u = hi16_in_low << 16;
  return v.f;
}

// ws layout (f32 indices):
//   stats [0,1024) | meanr [1024,1152) | pmax [1152,66688)   (1024 blocks x 64)
//   ushort wb = (ushort*)(wsf+66688):
//     BM   [16 j][32]  @0     (M' = W_lq' W_rk'^T, kk 0..10 = M'[kk][j])
//     BL   [64 c][32]  @512   (kk 0..9 = W_l[kk][c], kk10 = b_l[c])
//     BRV2 [64 c][32]  @2560  (kk 0..12 = (W_r.W_v^T)[kk][c], kk13 = b_rv[c])
//     BT   [64 c][64]  @4608  (W_t)
//     tg   [N][B][64]  @8704  (t, bf16, n-major: n*4096 + b*64 + c)
// A-tile k-slots: 0..9 = x, 10 = 1, 11..15 = 0, 16..28 = y, 29 = 1, 30,31 = 0.

// ---- k0: weight prep -----------------------------------------------------
__global__ void k0_prep(const float* __restrict__ W_l, const float* __restrict__ b_l,
                        const float* __restrict__ W_r, const float* __restrict__ b_r,
                        const float* __restrict__ W_qk, const float* __restrict__ W_v,
                        const float* __restrict__ b_v, const float* __restrict__ W_t,
                        float* __restrict__ wsf) {
  const int tid = threadIdx.x;
  unsigned short* wb   = (unsigned short*)(wsf + 66688);
  unsigned short* BM   = wb;
  unsigned short* BL   = wb + 512;
  unsigned short* BRV2 = wb + 2560;
  unsigned short* BT   = wb + 4608;
  if (blockIdx.x == 0) {
    __shared__ float Wlq[11 * 16], Wrk[14 * 16];
    for (int idx = tid; idx < 11 * 16; idx += 256) {
      int i = idx >> 4, d = idx & 15;
      const float* a = (i < 10) ? (W_l + i * 64) : b_l;
      float s = 0.f;
      for (int c = 0; c < 64; ++c) s = fmaf(a[c], W_qk[d * 64 + c], s);
      Wlq[idx] = s;
    }
    for (int idx = tid; idx < 14 * 16; idx += 256) {
      int j = idx >> 4, d = idx & 15;
      const float* a = (j < 13) ? (W_r + j * 64) : b_r;
      float s = 0.f;
      for (int c = 0; c < 64; ++c) s = fmaf(a[c], W_qk[d * 64 + c], s);
      Wrk[idx] = s;
    }
    __syncthreads();
    for (int idx = tid; idx < 512; idx += 256) {
      int j = idx >> 5, kk = idx & 31;
      unsigned short o = 0;
      if (j < 14 && kk < 11) {
        float s = 0.f;
        for (int d = 0; d < 16; ++d) s = fmaf(Wlq[kk * 16 + d], Wrk[j * 16 + d], s);
        o = f2bf(s);
      }
      BM[idx] = o;
    }
  } else if (blockIdx.x == 1) {
    for (int idx = tid; idx < 2048; idx += 256) {
      int c = idx >> 5, kk = idx & 31;
      unsigned short o = 0;
      if (kk < 13) {
        float s = 0.f;
        for (int j = 0; j < 64; ++j) s = fmaf(W_r[kk * 64 + j], W_v[c * 64 + j], s);
        o = f2bf(s);
      } else if (kk == 13) {
        float s = b_v[c];
        for (int j = 0; j < 64; ++j) s = fmaf(b_r[j], W_v[c * 64 + j], s);
        o = f2bf(s);
      }
      BRV2[idx] = o;
    }
  } else if (blockIdx.x == 2) {
    for (int idx = tid; idx < 2048; idx += 256) {
      int c = idx >> 5, kk = idx & 31;
      unsigned short o = 0;
      if (kk < 10) o = f2bf(W_l[kk * 64 + c]);
      else if (kk == 10) o = f2bf(b_l[c]);
      BL[idx] = o;
    }
    for (int i = tid; i < 1024; i += 256) wsf[i] = 0.f;
  } else {
    for (int i = tid; i < 4096; i += 256) BT[i] = f2bf(W_t[i]);
  }
}

// ---- k1: fused per-point chain, TWO points per block (lockstep) ----------
__global__ __launch_bounds__(256, 4)
void k1_attn(const float* __restrict__ x, const float* __restrict__ y,
             const float* __restrict__ wsf, const float* __restrict__ b_t,
             float* __restrict__ stats) {
  // LDS: 18688 shorts (37376 B) -> 4 blocks/CU (scr aliased onto dead Axy)
  __shared__ __align__(16) short lds[18688];
  // scr aliases the Axy region: Axy is dead after the E-phase MFMAs (barrier S1b
  // separates the last Axy read from the first scr write).
  float* const scr = (float*)lds;
  // carve: Axy[2][64*40] | YT[2][16*72] | awZ[2][4][16*72] | GU[2][4][16*16]
  short* const Axy[2] = {lds, lds + 2560};
  short* const YTb[2] = {lds + 5120, lds + 6272};
  short* const awB    = lds + 7424;    // (p*4+w)*1152
  short* const guB    = lds + 16640;   // (p*4+w)*256

  const unsigned short* wb   = (const unsigned short*)(wsf + 66688);
  const unsigned short* BM   = wb;
  const unsigned short* BL   = wb + 512;
  const unsigned short* BRV2 = wb + 2560;
  const unsigned short* BT   = wb + 4608;
  unsigned short* tg = (unsigned short*)(wsf + 66688) + 8704;

  const int tid  = threadIdx.x;
  const int w    = tid >> 6;
  const int lane = tid & 63;
  const int l15  = lane & 15;
  const int q    = lane >> 4;
  const int r0   = w * 16;
  const int n0   = blockIdx.x * 2;
  short* const aw[2] = {awB + w * 1152, awB + (4 + w) * 1152};
  short* const gu[2] = {guB + w * 256,  guB + (4 + w) * 256};

  // ---- stage x,y for both points ----
  {
    const int b = tid >> 2, i = tid & 3;
#pragma unroll
    for (int p = 0; p < 2; ++p) {
      const float* xp = x + ((size_t)b * N_ + n0 + p) * 10;
      const float* yp = y + ((size_t)b * N_ + n0 + p) * 13;
      short* Ar = Axy[p] + b * 40;
      Ar[i]     = (short)f2bf(xp[i]);
      Ar[i + 4] = (short)f2bf(xp[i + 4]);
      short v8 = 0;
      if (i < 2) v8 = (short)f2bf(xp[i + 8]);
      else if (i == 2) v8 = (short)0x3F80;          // xhat "1"
      Ar[i + 8]  = v8;
      Ar[i + 12] = 0;
      const short y0 = (short)f2bf(yp[i]);
      const short y1 = (short)f2bf(yp[i + 4]);
      const short y2 = (short)f2bf(yp[i + 8]);
      short y3 = 0;
      if (i == 0) y3 = (short)f2bf(yp[12]);
      else if (i == 1) y3 = (short)0x3F80;          // yhat "1"
      Ar[16 + i] = y0;  Ar[20 + i] = y1;  Ar[24 + i] = y2;  Ar[28 + i] = y3;
      short* YT = YTb[p];
      YT[i * 72 + b] = y0;  YT[(i + 4) * 72 + b] = y1;
      YT[(i + 8) * 72 + b] = y2;  YT[(i + 12) * 72 + b] = y3;
    }
  }
  __syncthreads();  // S1

  const short8 z8 = {0, 0, 0, 0, 0, 0, 0, 0};
  const f32x4 zero4 = {0.f, 0.f, 0.f, 0.f};

  // hoisted weight B-frags (shared across both points)
  const short8 bmF = *(const short8*)&BM[l15 * 32 + q * 8];
  short8 blF[4];
#pragma unroll
  for (int f = 0; f < 4; ++f) blF[f] = *(const short8*)&BL[(f * 16 + l15) * 32 + q * 8];

  // ---- G = xhat M', X = xhat [W_l;b_l] ----
  f32x4 X[2][4];
#pragma unroll
  for (int p = 0; p < 2; ++p) {
    const short8 aA = *(const short8*)&Axy[p][(r0 + l15) * 40 + q * 8];
    f32x4 G = MFMA16(aA, bmF, zero4);
#pragma unroll
    for (int f = 0; f < 4; ++f) X[p][f] = MFMA16(aA, blF[f], zero4);
#pragma unroll
    for (int j = 0; j < 4; ++j) gu[p][(q * 4 + j) * 16 + l15] = (short)f2bf(G[j]);
  }

  // ---- E = G yhat^T ----
  f32x4 E[2][4];
#pragma unroll
  for (int p = 0; p < 2; ++p) {
    short8 aG = z8;
    if (q < 2) aG = *(const short8*)&gu[p][l15 * 16 + q * 8];
#pragma unroll
    for (int f = 0; f < 4; ++f) {
      short8 bk = z8;
      if (q < 2) bk = *(const short8*)&Axy[p][(f * 16 + l15) * 40 + 16 + q * 8];
      E[p][f] = MFMA16(aG, bk, zero4);
    }
  }
  __syncthreads();  // S1b: last Axy reads done -> scr alias is now safe

  // ---- softmax over e (no max-subtract; |E|<<1, validated R4/R5) ----
  float inv_r[2][4];
#pragma unroll
  for (int p = 0; p < 2; ++p)
#pragma unroll
    for (int j = 0; j < 4; ++j) {
      float s = 0.f;
#pragma unroll
      for (int f = 0; f < 4; ++f) { E[p][f][j] = __expf(E[p][f][j]); s += E[p][f][j]; }
      s += __shfl_xor(s, 1);
      s += __shfl_xor(s, 2);
      s += __shfl_xor(s, 4);
      s += __shfl_xor(s, 8);
      inv_r[p][j] = 1.0f / s;
    }
  // ---- column sums (L1 renorm) ----
#pragma unroll
  for (int p = 0; p < 2; ++p)
#pragma unroll
    for (int f = 0; f < 4; ++f) {
      float cs = E[p][f][0] * inv_r[p][0] + E[p][f][1] * inv_r[p][1] +
                 E[p][f][2] * inv_r[p][2] + E[p][f][3] * inv_r[p][3];
      cs += __shfl_xor(cs, 16);
      cs += __shfl_xor(cs, 32);
      if (lane < 16) scr[p * 256 + w * 64 + f * 16 + l15] = cs;
    }
  __syncthreads();  // S2

  // ---- attn tiles ----
#pragma unroll
  for (int p = 0; p < 2; ++p) {
#pragma unroll
    for (int f = 0; f < 4; ++f) {
      const int col = f * 16 + l15;
      const float* sp = scr + p * 256;
      const float csv = 1.0f / (1e-9f + sp[col] + sp[64 + col] + sp[128 + col] + sp[192 + col]);
#pragma unroll
      for (int j = 0; j < 4; ++j)
        aw[p][(q * 4 + j) * 72 + col] = (short)f2bf(E[p][f][j] * inv_r[p][j] * csv);
    }
  }

  // ---- U = attn yhat ; yr = U [W_rv;b_rv] ; Z = X - yr ----
  short8 brvF[4];
#pragma unroll
  for (int f = 0; f < 4; ++f) brvF[f] = *(const short8*)&BRV2[(f * 16 + l15) * 32 + q * 8];
#pragma unroll
  for (int p = 0; p < 2; ++p) {
    const short8 aA0 = *(const short8*)&aw[p][l15 * 72 + q * 8];
    const short8 aA1 = *(const short8*)&aw[p][l15 * 72 + 32 + q * 8];
    f32x4 U = MFMA16(aA0, *(const short8*)&YTb[p][l15 * 72 + q * 8], zero4);
    U = MFMA16(aA1, *(const short8*)&YTb[p][l15 * 72 + 32 + q * 8], U);
#pragma unroll
    for (int j = 0; j < 4; ++j) gu[p][(q * 4 + j) * 16 + l15] = (short)f2bf(U[j]);
    short8 aU = z8;
    if (q < 2) aU = *(const short8*)&gu[p][l15 * 16 + q * 8];
#pragma unroll
    for (int f = 0; f < 4; ++f) {
      f32x4 yr = MFMA16(aU, brvF[f], zero4);
#pragma unroll
      for (int j = 0; j < 4; ++j)
        aw[p][(q * 4 + j) * 72 + f * 16 + l15] = (short)f2bf(X[p][f][j] - yr[j]);
    }
  }

  // ---- t = Z W_t^T + b_t ; stats in registers; ALSO t^T for coalesced store
  // Transposed MFMA reuses the SAME fragment loads (A/B frags share [row][k]
  // layout); lane then holds 4 consecutive channels -> pack to 8B store.
  f32x4 t[2][4];
  float sRed[2][4], ssRed[2][4];
  uint2 pk[2][4];
  float4 btv[4];
#pragma unroll
  for (int f = 0; f < 4; ++f) btv[f] = *(const float4*)&b_t[f * 16 + q * 4];
#pragma unroll
  for (int p = 0; p < 2; ++p) {
    const short8 aZ0 = *(const short8*)&aw[p][l15 * 72 + q * 8];
    const short8 aZ1 = *(const short8*)&aw[p][l15 * 72 + 32 + q * 8];
#pragma unroll
    for (int f = 0; f < 4; ++f) {
      const int c = f * 16 + l15;
      const float bT = b_t[c];
      const short8 bt0 = *(const short8*)&BT[c * 64 + q * 8];
      const short8 bt1 = *(const short8*)&BT[c * 64 + 32 + q * 8];
      t[p][f] = MFMA16(aZ0, bt0, ((f32x4){bT, bT, bT, bT}));
      t[p][f] = MFMA16(aZ1, bt1, t[p][f]);
      float s = 0.f, ss = 0.f;
#pragma unroll
      for (int j = 0; j < 4; ++j) { s += t[p][f][j]; ss = fmaf(t[p][f][j], t[p][f][j], ss); }
      s  += __shfl_xor(s, 16);  s  += __shfl_xor(s, 32);
      ss += __shfl_xor(ss, 16); ss += __shfl_xor(ss, 32);
      sRed[p][f] = s; ssRed[p][f] = ss;
      // t^T tile: D[m=c, n=b]; lane's 4 regs = 4 consecutive channels of one b
      f32x4 tc = MFMA16(bt0, aZ0, ((f32x4){btv[f].x, btv[f].y, btv[f].z, btv[f].w}));
      tc = MFMA16(bt1, aZ1, tc);
      pk[p][f].x = (unsigned)f2bf(tc[0]) | ((unsigned)f2bf(tc[1]) << 16);
      pk[p][f].y = (unsigned)f2bf(tc[2]) | ((unsigned)f2bf(tc[3]) << 16);
    }
  }
  __syncthreads();  // S3: colsum reads done; scr reusable
#pragma unroll
  for (int p = 0; p < 2; ++p)
#pragma unroll
    for (int f = 0; f < 4; ++f)
      if (lane < 16) {
        scr[p * 512 + w * 64 + f * 16 + l15]       = sRed[p][f];
        scr[p * 512 + 256 + w * 64 + f * 16 + l15] = ssRed[p][f];
      }
  __syncthreads();  // S4
  if (tid < 128) {
    const int p = tid >> 6, c = tid & 63;
    const float* sp = scr + p * 512;
    const float s  = sp[c] + sp[64 + c] + sp[128 + c] + sp[192 + c];
    const float ss = sp[256 + c] + sp[320 + c] + sp[384 + c] + sp[448 + c];
    float* st = stats + ((n0 + p) & 7) * 128;
    atomicAdd(&st[c], s);
    atomicAdd(&st[64 + c], ss);
  }
  // ---- tg stores LAST: 8 x dwordx2 per thread, n-major [n][b][c] ----
#pragma unroll
  for (int p = 0; p < 2; ++p)
#pragma unroll
    for (int f = 0; f < 4; ++f)
      *(uint2*)&tg[(size_t)(n0 + p) * 4096 + (size_t)(r0 + l15) * 64 + f * 16 + q * 4] =
          pk[p][f];
}

// ---- k2: finalize BN stats ----------------------------------------------
__global__ void k2_stats(const float* __restrict__ stats, float* __restrict__ meanr) {
  const int c = threadIdx.x;
  if (c < 64) {
    float s = 0.f, ss = 0.f;
    for (int r = 0; r < 8; ++r) { s += stats[r * 128 + c]; ss += stats[r * 128 + 64 + c]; }
    const float inv = 1.0f / (float)(B_ * N_);
    const float mu = s * inv;
    const float var = fmaf(ss, inv, -mu * mu);
    meanr[c] = mu;
    meanr[64 + c] = rsqrtf(var + 1e-5f);
  }
}

// ---- k3: recompute X (f32), BN+ReLU+residual, partial max over n ---------
__global__ __launch_bounds__(256)
void k3_max(const float* __restrict__ x, const float* __restrict__ W_l,
            const float* __restrict__ b_l, const float* __restrict__ gamma,
            const float* __restrict__ beta, const unsigned short* __restrict__ tg,
            const float* __restrict__ meanr, float* __restrict__ pmax)
{
  const int b = blockIdx.x >> 4;      // 0..63
  const int chunk = blockIdx.x & 15;  // 512 n's each
  const int wv = threadIdx.x >> 6;
  const int lane = threadIdx.x & 63;
  const int c0 = (lane & 15) * 4;
  const int nsub = lane >> 4;
  float4 wl4[10];
#pragma unroll
  for (int k = 0; k < 10; ++k) wl4[k] = *(const float4*)&W_l[k * 64 + c0];
  const float4 bl  = *(const float4*)&b_l[c0];
  const float4 g   = *(const float4*)&gamma[c0];
  const float4 be  = *(const float4*)&beta[c0];
  const float4 mu  = *(const float4*)&meanr[c0];
  const float4 rs  = *(const float4*)&meanr[64 + c0];
  float4 grs, bmb;
  grs.x = g.x * rs.x; grs.y = g.y * rs.y; grs.z = g.z * rs.z; grs.w = g.w * rs.w;
  bmb.x = be.x - mu.x * grs.x; bmb.y = be.y - mu.y * grs.y;
  bmb.z = be.z - mu.z * grs.z; bmb.w = be.w - mu.w * grs.w;
  float4 m = {-1e30f, -1e30f, -1e30f, -1e30f};
  const int n0 = chunk * 512 + wv * 128 + nsub;
  for (int jj = 0; jj < 32; ++jj) {
    const int n = n0 + jj * 4;
    const uint2 tv = *(const uint2*)&tg[(size_t)n * 4096 + (b << 6) + c0];
    const float* xp = x + ((size_t)b * N_ + n) * 10;
    float4 X = bl;
#pragma unroll
    for (int k = 0; k < 10; ++k) {
      const float xk = xp[k];
      X.x = fmaf(xk, wl4[k].x, X.x); X.y = fmaf(xk, wl4[k].y, X.y);
      X.z = fmaf(xk, wl4[k].z, X.z); X.w = fmaf(xk, wl4[k].w, X.w);
    }
    const float t0 = bf2f(tv.x & 0xFFFFu), t1 = bf2f(tv.x >> 16);
    const float t2 = bf2f(tv.y & 0xFFFFu), t3 = bf2f(tv.y >> 16);
    m.x = fmaxf(m.x, X.x + fmaxf(fmaf(t0, grs.x, bmb.x), 0.f));
    m.y = fmaxf(m.y, X.y + fmaxf(fmaf(t1, grs.y, bmb.y), 0.f));
    m.z = fmaxf(m.z, X.z + fmaxf(fmaf(t2, grs.z, bmb.z), 0.f));
    m.w = fmaxf(m.w, X.w + fmaxf(fmaf(t3, grs.w, bmb.w), 0.f));
  }
  m.x = fmaxf(m.x, __shfl_xor(m.x, 16)); m.y = fmaxf(m.y, __shfl_xor(m.y, 16));
  m.z = fmaxf(m.z, __shfl_xor(m.z, 16)); m.w = fmaxf(m.w, __shfl_xor(m.w, 16));
  m.x = fmaxf(m.x, __shfl_xor(m.x, 32)); m.y = fmaxf(m.y, __shfl_xor(m.y, 32));
  m.z = fmaxf(m.z, __shfl_xor(m.z, 32)); m.w = fmaxf(m.w, __shfl_xor(m.w, 32));
  __shared__ float sm[4][64];
  if (lane < 16) *(float4*)&sm[wv][c0] = m;
  __syncthreads();
  if (threadIdx.x < 64) {
    const float r = fmaxf(fmaxf(sm[0][threadIdx.x], sm[1][threadIdx.x]),
                          fmaxf(sm[2][threadIdx.x], sm[3][threadIdx.x]));
    pmax[(size_t)blockIdx.x * 64 + threadIdx.x] = r;
  }
}

// ---- k4: final max over chunks -------------------------------------------
__global__ void k4_final(const float* __restrict__ pmax, float* __restrict__ out) {
  const int b = blockIdx.x, c = threadIdx.x;
  float m = -1e30f;
  for (int ch = 0; ch < 16; ++ch) m = fmaxf(m, pmax[((size_t)b * 16 + ch) * 64 + c]);
  out[b * 64 + c] = m;
}

// ---- launcher -------------------------------------------------------------
extern "C" void kernel_launch(void* const* d_in, const int* in_sizes, int n_in,
                              void* d_out, int out_size, void* d_ws, size_t ws_size,
                              hipStream_t stream) {
  const float* x     = (const float*)d_in[0];
  const float* y     = (const float*)d_in[1];
  const float* W_l   = (const float*)d_in[2];
  const float* b_l   = (const float*)d_in[3];
  const float* W_r   = (const float*)d_in[4];
  const float* b_r   = (const float*)d_in[5];
  const float* W_qk  = (const float*)d_in[6];
  const float* W_v   = (const float*)d_in[7];
  const float* b_v   = (const float*)d_in[8];
  const float* W_t   = (const float*)d_in[9];
  const float* b_t   = (const float*)d_in[10];
  const float* gamma = (const float*)d_in[11];
  const float* beta  = (const float*)d_in[12];
  float* out = (float*)d_out;

  float* wsf = (float*)d_ws;
  float* stats = wsf;
  float* meanr = wsf + 1024;
  float* pmax  = wsf + 1152;
  const unsigned short* tg = (const unsigned short*)(wsf + 66688) + 8704;

  hipLaunchKernelGGL(k0_prep, dim3(4), dim3(256), 0, stream,
                     W_l, b_l, W_r, b_r, W_qk, W_v, b_v, W_t, wsf);
  hipLaunchKernelGGL(k1_attn, dim3(N_ / 2), dim3(256), 0, stream,
                     x, y, wsf, b_t, stats);
  hipLaunchKernelGGL(k2_stats, dim3(1), dim3(64), 0, stream, stats, meanr);
  hipLaunchKernelGGL(k3_max, dim3(1024), dim3(256), 0, stream,
                     x, W_l, b_l, gamma, beta, tg, meanr, pmax);
  hipLaunchKernelGGL(k4_final, dim3(64), dim3(64), 0, stream, pmax, out);
}

// Round 2
// 202.695 us; speedup vs baseline: 1.0278x; 1.0118x over previous
//
#include <hip/hip_runtime.h>

#define B_ 64
#define N_ 8192

using short8 = __attribute__((ext_vector_type(8))) short;  // 8 bf16 (4 VGPRs)
using f32x4  = __attribute__((ext_vector_type(4))) float;

#define MFMA16(a, b, c) __builtin_amdgcn_mfma_f32_16x16x32_bf16((a), (b), (c), 0, 0, 0)

// round-half-up bf16: same 2^-9 max-rel-err bound as RNE, 2 VALU instrs
__device__ inline unsigned short f2bf(float f) {
  union { float f; unsigned int u; } v; v.f = f;
  return (unsigned short)((v.u + 0x8000u) >> 16);
}
__device__ inline float bf2f(unsigned int hi16_in_low) {
  union { unsigned int u; float f; } v; v.u = hi16_in_low << 16;
  return v.f;
}
__device__ inline unsigned u2(float a, float b) {
  return (unsigned)f2bf(a) | ((unsigned)f2bf(b) << 16);
}
// y element store: Ar slot 16+f (p0) or Ar1 slot 3+f (p1, = Ar0+2563+f);
// YT0 row f (p0) or YT1 row f-13 (= YT0 + 72f + 216). Branch-free.
__device__ inline void put_y(short* Ar0, short* YT0, int b, int f, unsigned short h) {
  const int s = (f >= 13) ? 1 : 0;
  Ar0[16 + f + 2547 * s] = (short)h;
  YT0[f * 72 + b + 216 * s] = (short)h;
}

// ws layout (f32 indices):
//   stats [0,1024) | meanr [1024,1152) (unused) | pmax [1152,66688)
//   ushort wb = (ushort*)(wsf+66688):
//     BM   [16 j][32]  @0     (M' = W_lq' W_rk'^T, kk 0..10 = M'[kk][j])
//     BL   [64 c][32]  @512   (kk 0..9 = W_l[kk][c], kk10 = b_l[c])
//     BRV2 [64 c][32]  @2560  (kk 0..12 = (W_r.W_v^T)[kk][c], kk13 = b_rv[c])
//     BT   [64 c][64]  @4608  (W_t)
//     tg   [N][B][64]  @8704  (t, bf16, n-major: n*4096 + b*64 + c)
// A-tile k-slots: 0..9 = x, 10 = 1, 11..15 = 0, 16..28 = y, 29 = 1, 30,31 = 0.

// ---- k0: weight prep -----------------------------------------------------
__global__ void k0_prep(const float* __restrict__ W_l, const float* __restrict__ b_l,
                        const float* __restrict__ W_r, const float* __restrict__ b_r,
                        const float* __restrict__ W_qk, const float* __restrict__ W_v,
                        const float* __restrict__ b_v, const float* __restrict__ W_t,
                        float* __restrict__ wsf) {
  const int tid = threadIdx.x;
  unsigned short* wb   = (unsigned short*)(wsf + 66688);
  unsigned short* BM   = wb;
  unsigned short* BL   = wb + 512;
  unsigned short* BRV2 = wb + 2560;
  unsigned short* BT   = wb + 4608;
  if (blockIdx.x == 0) {
    __shared__ float Wlq[11 * 16], Wrk[14 * 16];
    for (int idx = tid; idx < 11 * 16; idx += 256) {
      int i = idx >> 4, d = idx & 15;
      const float* a = (i < 10) ? (W_l + i * 64) : b_l;
      float s = 0.f;
      for (int c = 0; c < 64; ++c) s = fmaf(a[c], W_qk[d * 64 + c], s);
      Wlq[idx] = s;
    }
    for (int idx = tid; idx < 14 * 16; idx += 256) {
      int j = idx >> 4, d = idx & 15;
      const float* a = (j < 13) ? (W_r + j * 64) : b_r;
      float s = 0.f;
      for (int c = 0; c < 64; ++c) s = fmaf(a[c], W_qk[d * 64 + c], s);
      Wrk[idx] = s;
    }
    __syncthreads();
    for (int idx = tid; idx < 512; idx += 256) {
      int j = idx >> 5, kk = idx & 31;
      unsigned short o = 0;
      if (j < 14 && kk < 11) {
        float s = 0.f;
        for (int d = 0; d < 16; ++d) s = fmaf(Wlq[kk * 16 + d], Wrk[j * 16 + d], s);
        o = f2bf(s);
      }
      BM[idx] = o;
    }
  } else if (blockIdx.x == 1) {
    for (int idx = tid; idx < 2048; idx += 256) {
      int c = idx >> 5, kk = idx & 31;
      unsigned short o = 0;
      if (kk < 13) {
        float s = 0.f;
        for (int j = 0; j < 64; ++j) s = fmaf(W_r[kk * 64 + j], W_v[c * 64 + j], s);
        o = f2bf(s);
      } else if (kk == 13) {
        float s = b_v[c];
        for (int j = 0; j < 64; ++j) s = fmaf(b_r[j], W_v[c * 64 + j], s);
        o = f2bf(s);
      }
      BRV2[idx] = o;
    }
  } else if (blockIdx.x == 2) {
    for (int idx = tid; idx < 2048; idx += 256) {
      int c = idx >> 5, kk = idx & 31;
      unsigned short o = 0;
      if (kk < 10) o = f2bf(W_l[kk * 64 + c]);
      else if (kk == 10) o = f2bf(b_l[c]);
      BL[idx] = o;
    }
    for (int i = tid; i < 1024; i += 256) wsf[i] = 0.f;
  } else {
    for (int i = tid; i < 4096; i += 256) BT[i] = f2bf(W_t[i]);
  }
}

// ---- k1: fused per-point chain, TWO points per block (lockstep) ----------
__global__ __launch_bounds__(256, 4)
void k1_attn(const float* __restrict__ x, const float* __restrict__ y,
             const float* __restrict__ wsf, const float* __restrict__ b_t,
             float* __restrict__ stats) {
  // LDS: 18688 shorts (37376 B) -> 4 blocks/CU (scr aliased onto dead Axy)
  __shared__ __align__(16) short lds[18688];
  float* const scr = (float*)lds;  // aliases Axy (dead after E; S1b fences)
  // carve: Axy[2][64*40] | YT[2][16*72] | awZ[2][4][16*72] | GU[2][4][16*16]
  short* const Axy[2] = {lds, lds + 2560};
  short* const YTb[2] = {lds + 5120, lds + 6272};
  short* const awB    = lds + 7424;    // (p*4+w)*1152
  short* const guB    = lds + 16640;   // (p*4+w)*256

  const unsigned short* wb   = (const unsigned short*)(wsf + 66688);
  const unsigned short* BM   = wb;
  const unsigned short* BL   = wb + 512;
  const unsigned short* BRV2 = wb + 2560;
  const unsigned short* BT   = wb + 4608;
  unsigned short* tg = (unsigned short*)(wsf + 66688) + 8704;

  const int tid  = threadIdx.x;
  const int w    = tid >> 6;
  const int lane = tid & 63;
  const int l15  = lane & 15;
  const int q    = lane >> 4;
  const int r0   = w * 16;
  const int n0   = blockIdx.x * 2;
  short* const aw[2] = {awB + w * 1152, awB + (4 + w) * 1152};
  short* const gu[2] = {guB + w * 256,  guB + (4 + w) * 256};

  // ---- stage x,y for both points (vectorized; wave w stages its own rows) ----
  {
    const int b = tid >> 2, i = tid & 3;
    const float* xb = x + ((size_t)b * N_ + n0) * 10;   // 20 f32, 16B aligned
    const float* yb = y + ((size_t)b * N_ + n0) * 13;   // 26 f32, 8B aligned
    short* const Ar0 = Axy[0] + b * 40;
    short* const Ar1 = Axy[1] + b * 40;
    short* const YT0 = YTb[0];
    // x: float4 chunk i (chunk 4 on i==0); boundary at float 10 is even -> pairs homogeneous
    {
      const float4 v = *(const float4*)(xb + 4 * i);
      const int g0 = 4 * i, g1 = 4 * i + 2;
      *(unsigned*)(Ar0 + (g0 >= 10 ? g0 + 2550 : g0)) = u2(v.x, v.y);
      *(unsigned*)(Ar0 + (g1 >= 10 ? g1 + 2550 : g1)) = u2(v.z, v.w);
      if (i == 0) {
        const float4 vv = *(const float4*)(xb + 16);
        *(unsigned*)(Ar1 + 6) = u2(vv.x, vv.y);
        *(unsigned*)(Ar1 + 8) = u2(vv.z, vv.w);
      }
    }
    if (i == 1) { *(unsigned*)(Ar1 + 10) = 0x3F80u; *(unsigned*)(Ar1 + 12) = 0u; *(unsigned*)(Ar1 + 14) = 0u; }
    if (i == 2) { *(unsigned*)(Ar0 + 10) = 0x3F80u; *(unsigned*)(Ar0 + 12) = 0u; *(unsigned*)(Ar0 + 14) = 0u; }
    // y: float2 pairs j = i, i+4, i+8 (+12 on i==0)
#pragma unroll
    for (int t = 0; t < 3; ++t) {
      const int j = i + 4 * t;
      const float2 v = *(const float2*)(yb + 2 * j);
      put_y(Ar0, YT0, b, 2 * j,     f2bf(v.x));
      put_y(Ar0, YT0, b, 2 * j + 1, f2bf(v.y));
    }
    if (i == 0) {
      const float2 v = *(const float2*)(yb + 24);
      put_y(Ar0, YT0, b, 24, f2bf(v.x));
      put_y(Ar0, YT0, b, 25, f2bf(v.y));
    }
    if (i == 3) {  // p0 y-tail consts
      Ar0[29] = (short)0x3F80; *(unsigned*)(Ar0 + 30) = 0u;
      YT0[13 * 72 + b] = (short)0x3F80; YT0[14 * 72 + b] = 0; YT0[15 * 72 + b] = 0;
    }
    if (i == 2) {  // p1 y-tail consts
      Ar1[29] = (short)0x3F80; *(unsigned*)(Ar1 + 30) = 0u;
      short* YT1 = YT0 + 1152;
      YT1[13 * 72 + b] = (short)0x3F80; YT1[14 * 72 + b] = 0; YT1[15 * 72 + b] = 0;
    }
  }
  // Wave w staged exactly its own A-rows (b = tid>>2 in [16w,16w+16)):
  // G/X needs only wave-local LDS completion, not the block barrier.
  asm volatile("s_waitcnt lgkmcnt(0)" ::: "memory");
  __builtin_amdgcn_sched_barrier(0);

  const short8 z8 = {0, 0, 0, 0, 0, 0, 0, 0};
  const f32x4 zero4 = {0.f, 0.f, 0.f, 0.f};

  // hoisted weight B-frags (shared across both points)
  const short8 bmF = *(const short8*)&BM[l15 * 32 + q * 8];
  short8 blF[4];
#pragma unroll
  for (int f = 0; f < 4; ++f) blF[f] = *(const short8*)&BL[(f * 16 + l15) * 32 + q * 8];

  // ---- G = xhat M', X = xhat [W_l;b_l] ---- (own rows only; pre-barrier)
  f32x4 X[2][4];
  __builtin_amdgcn_s_setprio(1);
#pragma unroll
  for (int p = 0; p < 2; ++p) {
    const short8 aA = *(const short8*)&Axy[p][(r0 + l15) * 40 + q * 8];
    f32x4 G = MFMA16(aA, bmF, zero4);
#pragma unroll
    for (int f = 0; f < 4; ++f) X[p][f] = MFMA16(aA, blF[f], zero4);
#pragma unroll
    for (int j = 0; j < 4; ++j) gu[p][(q * 4 + j) * 16 + l15] = (short)f2bf(G[j]);
  }
  __builtin_amdgcn_s_setprio(0);
  __syncthreads();  // S1: all waves' staging visible (E reads all rows)

  // ---- E = G yhat^T ----
  f32x4 E[2][4];
  __builtin_amdgcn_s_setprio(1);
#pragma unroll
  for (int p = 0; p < 2; ++p) {
    short8 aG = z8;
    if (q < 2) aG = *(const short8*)&gu[p][l15 * 16 + q * 8];
#pragma unroll
    for (int f = 0; f < 4; ++f) {
      short8 bk = z8;
      if (q < 2) bk = *(const short8*)&Axy[p][(f * 16 + l15) * 40 + 16 + q * 8];
      E[p][f] = MFMA16(aG, bk, zero4);
    }
  }
  __builtin_amdgcn_s_setprio(0);
  __syncthreads();  // S1b: last Axy reads done -> scr alias is now safe

  // ---- softmax over e (no max-subtract; |E|<<1, validated R4/R5) ----
  float inv_r[2][4];
#pragma unroll
  for (int p = 0; p < 2; ++p)
#pragma unroll
    for (int j = 0; j < 4; ++j) {
      float s = 0.f;
#pragma unroll
      for (int f = 0; f < 4; ++f) { E[p][f][j] = __expf(E[p][f][j]); s += E[p][f][j]; }
      s += __shfl_xor(s, 1);
      s += __shfl_xor(s, 2);
      s += __shfl_xor(s, 4);
      s += __shfl_xor(s, 8);
      inv_r[p][j] = 1.0f / s;
    }
  // ---- column sums (L1 renorm) ----
#pragma unroll
  for (int p = 0; p < 2; ++p)
#pragma unroll
    for (int f = 0; f < 4; ++f) {
      float cs = E[p][f][0] * inv_r[p][0] + E[p][f][1] * inv_r[p][1] +
                 E[p][f][2] * inv_r[p][2] + E[p][f][3] * inv_r[p][3];
      cs += __shfl_xor(cs, 16);
      cs += __shfl_xor(cs, 32);
      if (lane < 16) scr[p * 256 + w * 64 + f * 16 + l15] = cs;
    }
  __syncthreads();  // S2

  // ---- attn tiles ----
#pragma unroll
  for (int p = 0; p < 2; ++p) {
#pragma unroll
    for (int f = 0; f < 4; ++f) {
      const int col = f * 16 + l15;
      const float* sp = scr + p * 256;
      const float csv = 1.0f / (1e-9f + sp[col] + sp[64 + col] + sp[128 + col] + sp[192 + col]);
#pragma unroll
      for (int j = 0; j < 4; ++j)
        aw[p][(q * 4 + j) * 72 + col] = (short)f2bf(E[p][f][j] * inv_r[p][j] * csv);
    }
  }

  // ---- U = attn yhat ; yr = U [W_rv;b_rv] ; Z = X - yr ----
  short8 brvF[4];
#pragma unroll
  for (int f = 0; f < 4; ++f) brvF[f] = *(const short8*)&BRV2[(f * 16 + l15) * 32 + q * 8];
  __builtin_amdgcn_s_setprio(1);
#pragma unroll
  for (int p = 0; p < 2; ++p) {
    const short8 aA0 = *(const short8*)&aw[p][l15 * 72 + q * 8];
    const short8 aA1 = *(const short8*)&aw[p][l15 * 72 + 32 + q * 8];
    f32x4 U = MFMA16(aA0, *(const short8*)&YTb[p][l15 * 72 + q * 8], zero4);
    U = MFMA16(aA1, *(const short8*)&YTb[p][l15 * 72 + 32 + q * 8], U);
#pragma unroll
    for (int j = 0; j < 4; ++j) gu[p][(q * 4 + j) * 16 + l15] = (short)f2bf(U[j]);
    short8 aU = z8;
    if (q < 2) aU = *(const short8*)&gu[p][l15 * 16 + q * 8];
#pragma unroll
    for (int f = 0; f < 4; ++f) {
      f32x4 yr = MFMA16(aU, brvF[f], zero4);
#pragma unroll
      for (int j = 0; j < 4; ++j)
        aw[p][(q * 4 + j) * 72 + f * 16 + l15] = (short)f2bf(X[p][f][j] - yr[j]);
    }
  }
  __builtin_amdgcn_s_setprio(0);

  // ---- t = Z W_t^T + b_t ; stats in registers; ALSO t^T for coalesced store
  f32x4 t[2][4];
  float sRed[2][4], ssRed[2][4];
  uint2 pk[2][4];
  float4 btv[4];
#pragma unroll
  for (int f = 0; f < 4; ++f) btv[f] = *(const float4*)&b_t[f * 16 + q * 4];
  __builtin_amdgcn_s_setprio(1);
#pragma unroll
  for (int p = 0; p < 2; ++p) {
    const short8 aZ0 = *(const short8*)&aw[p][l15 * 72 + q * 8];
    const short8 aZ1 = *(const short8*)&aw[p][l15 * 72 + 32 + q * 8];
#pragma unroll
    for (int f = 0; f < 4; ++f) {
      const int c = f * 16 + l15;
      const float bT = b_t[c];
      const short8 bt0 = *(const short8*)&BT[c * 64 + q * 8];
      const short8 bt1 = *(const short8*)&BT[c * 64 + 32 + q * 8];
      t[p][f] = MFMA16(aZ0, bt0, ((f32x4){bT, bT, bT, bT}));
      t[p][f] = MFMA16(aZ1, bt1, t[p][f]);
      float s = 0.f, ss = 0.f;
#pragma unroll
      for (int j = 0; j < 4; ++j) { s += t[p][f][j]; ss = fmaf(t[p][f][j], t[p][f][j], ss); }
      s  += __shfl_xor(s, 16);  s  += __shfl_xor(s, 32);
      ss += __shfl_xor(ss, 16); ss += __shfl_xor(ss, 32);
      sRed[p][f] = s; ssRed[p][f] = ss;
      // t^T tile: D[m=c, n=b]; lane's 4 regs = 4 consecutive channels of one b
      f32x4 tc = MFMA16(bt0, aZ0, ((f32x4){btv[f].x, btv[f].y, btv[f].z, btv[f].w}));
      tc = MFMA16(bt1, aZ1, tc);
      pk[p][f].x = (unsigned)f2bf(tc[0]) | ((unsigned)f2bf(tc[1]) << 16);
      pk[p][f].y = (unsigned)f2bf(tc[2]) | ((unsigned)f2bf(tc[3]) << 16);
    }
  }
  __builtin_amdgcn_s_setprio(0);
  __syncthreads();  // S3: colsum reads done; scr reusable
#pragma unroll
  for (int p = 0; p < 2; ++p)
#pragma unroll
    for (int f = 0; f < 4; ++f)
      if (lane < 16) {
        scr[p * 512 + w * 64 + f * 16 + l15]       = sRed[p][f];
        scr[p * 512 + 256 + w * 64 + f * 16 + l15] = ssRed[p][f];
      }
  __syncthreads();  // S4
  if (tid < 128) {
    const int p = tid >> 6, c = tid & 63;
    const float* sp = scr + p * 512;
    const float s  = sp[c] + sp[64 + c] + sp[128 + c] + sp[192 + c];
    const float ss = sp[256 + c] + sp[320 + c] + sp[384 + c] + sp[448 + c];
    float* st = stats + ((n0 + p) & 7) * 128;
    atomicAdd(&st[c], s);
    atomicAdd(&st[64 + c], ss);
  }
  // ---- tg stores LAST: 8 x dwordx2 per thread, n-major [n][b][c] ----
#pragma unroll
  for (int p = 0; p < 2; ++p)
#pragma unroll
    for (int f = 0; f < 4; ++f)
      *(uint2*)&tg[(size_t)(n0 + p) * 4096 + (size_t)(r0 + l15) * 64 + f * 16 + q * 4] =
          pk[p][f];
}

// ---- k3: BN-stats finalize (folded k2), X recompute from LDS x-slab,
//          BN+ReLU+residual, partial max over n ---------------------------
__global__ __launch_bounds__(256)
void k3_max(const float* __restrict__ x, const float* __restrict__ W_l,
            const float* __restrict__ b_l, const float* __restrict__ gamma,
            const float* __restrict__ beta, const unsigned short* __restrict__ tg,
            const float* __restrict__ stats, float* __restrict__ pmax)
{
  const int b = blockIdx.x >> 4;      // 0..63
  const int chunk = blockIdx.x & 15;  // 512 n's each
  __shared__ __align__(16) float xs[512 * 10];  // block's x-slab, 20 KB
  __shared__ float mr[128];
  __shared__ float sm[4][64];
  // cooperative x-slab stage: 1280 float4, fully coalesced
  {
    const float4* src = (const float4*)(x + ((size_t)b * N_ + (size_t)chunk * 512) * 10);
    float4* dst = (float4*)xs;
#pragma unroll
    for (int t = 0; t < 5; ++t) dst[threadIdx.x + 256 * t] = src[threadIdx.x + 256 * t];
  }
  // fold former k2: finalize BN stats per channel (runs under the staging loads)
  if (threadIdx.x < 64) {
    const int c = threadIdx.x;
    float s = 0.f, ss = 0.f;
    for (int r = 0; r < 8; ++r) { s += stats[r * 128 + c]; ss += stats[r * 128 + 64 + c]; }
    const float inv = 1.0f / (float)(B_ * N_);
    const float mu = s * inv;
    const float var = fmaf(ss, inv, -mu * mu);
    mr[c] = mu;
    mr[64 + c] = rsqrtf(var + 1e-5f);
  }
  const int wv = threadIdx.x >> 6;
  const int lane = threadIdx.x & 63;
  const int c0 = (lane & 15) * 4;
  const int nsub = lane >> 4;
  float4 wl4[10];
#pragma unroll
  for (int k = 0; k < 10; ++k) wl4[k] = *(const float4*)&W_l[k * 64 + c0];
  const float4 bl  = *(const float4*)&b_l[c0];
  const float4 g   = *(const float4*)&gamma[c0];
  const float4 be  = *(const float4*)&beta[c0];
  __syncthreads();
  const float4 mu  = *(const float4*)&mr[c0];
  const float4 rs  = *(const float4*)&mr[64 + c0];
  float4 grs, bmb;
  grs.x = g.x * rs.x; grs.y = g.y * rs.y; grs.z = g.z * rs.z; grs.w = g.w * rs.w;
  bmb.x = be.x - mu.x * grs.x; bmb.y = be.y - mu.y * grs.y;
  bmb.z = be.z - mu.z * grs.z; bmb.w = be.w - mu.w * grs.w;
  float4 m = {-1e30f, -1e30f, -1e30f, -1e30f};
  const int ln0 = wv * 128 + nsub;
#pragma unroll 2
  for (int jj = 0; jj < 32; ++jj) {
    const int ln = ln0 + jj * 4;                 // local row in [0,512)
    const uint2 tv = *(const uint2*)&tg[(size_t)(chunk * 512 + ln) * 4096 + (b << 6) + c0];
    const float2* xr = (const float2*)(xs + ln * 10);
    float4 X = bl;
#pragma unroll
    for (int k = 0; k < 5; ++k) {
      const float2 xk = xr[k];
      X.x = fmaf(xk.x, wl4[2 * k].x, X.x); X.y = fmaf(xk.x, wl4[2 * k].y, X.y);
      X.z = fmaf(xk.x, wl4[2 * k].z, X.z); X.w = fmaf(xk.x, wl4[2 * k].w, X.w);
      X.x = fmaf(xk.y, wl4[2 * k + 1].x, X.x); X.y = fmaf(xk.y, wl4[2 * k + 1].y, X.y);
      X.z = fmaf(xk.y, wl4[2 * k + 1].z, X.z); X.w = fmaf(xk.y, wl4[2 * k + 1].w, X.w);
    }
    const float t0 = bf2f(tv.x & 0xFFFFu), t1 = bf2f(tv.x >> 16);
    const float t2 = bf2f(tv.y & 0xFFFFu), t3 = bf2f(tv.y >> 16);
    m.x = fmaxf(m.x, X.x + fmaxf(fmaf(t0, grs.x, bmb.x), 0.f));
    m.y = fmaxf(m.y, X.y + fmaxf(fmaf(t1, grs.y, bmb.y), 0.f));
    m.z = fmaxf(m.z, X.z + fmaxf(fmaf(t2, grs.z, bmb.z), 0.f));
    m.w = fmaxf(m.w, X.w + fmaxf(fmaf(t3, grs.w, bmb.w), 0.f));
  }
  m.x = fmaxf(m.x, __shfl_xor(m.x, 16)); m.y = fmaxf(m.y, __shfl_xor(m.y, 16));
  m.z = fmaxf(m.z, __shfl_xor(m.z, 16)); m.w = fmaxf(m.w, __shfl_xor(m.w, 16));
  m.x = fmaxf(m.x, __shfl_xor(m.x, 32)); m.y = fmaxf(m.y, __shfl_xor(m.y, 32));
  m.z = fmaxf(m.z, __shfl_xor(m.z, 32)); m.w = fmaxf(m.w, __shfl_xor(m.w, 32));
  if (lane < 16) *(float4*)&sm[wv][c0] = m;
  __syncthreads();
  if (threadIdx.x < 64) {
    const float r = fmaxf(fmaxf(sm[0][threadIdx.x], sm[1][threadIdx.x]),
                          fmaxf(sm[2][threadIdx.x], sm[3][threadIdx.x]));
    pmax[(size_t)blockIdx.x * 64 + threadIdx.x] = r;
  }
}

// ---- k4: final max over chunks -------------------------------------------
__global__ void k4_final(const float* __restrict__ pmax, float* __restrict__ out) {
  const int b = blockIdx.x, c = threadIdx.x;
  float m = -1e30f;
  for (int ch = 0; ch < 16; ++ch) m = fmaxf(m, pmax[((size_t)b * 16 + ch) * 64 + c]);
  out[b * 64 + c] = m;
}

// ---- launcher -------------------------------------------------------------
extern "C" void kernel_launch(void* const* d_in, const int* in_sizes, int n_in,
                              void* d_out, int out_size, void* d_ws, size_t ws_size,
                              hipStream_t stream) {
  const float* x     = (const float*)d_in[0];
  const float* y     = (const float*)d_in[1];
  const float* W_l   = (const float*)d_in[2];
  const float* b_l   = (const float*)d_in[3];
  const float* W_r   = (const float*)d_in[4];
  const float* b_r   = (const float*)d_in[5];
  const float* W_qk  = (const float*)d_in[6];
  const float* W_v   = (const float*)d_in[7];
  const float* b_v   = (const float*)d_in[8];
  const float* W_t   = (const float*)d_in[9];
  const float* b_t   = (const float*)d_in[10];
  const float* gamma = (const float*)d_in[11];
  const float* beta  = (const float*)d_in[12];
  float* out = (float*)d_out;

  float* wsf = (float*)d_ws;
  float* stats = wsf;
  float* pmax  = wsf + 1152;
  const unsigned short* tg = (const unsigned short*)(wsf + 66688) + 8704;

  hipLaunchKernelGGL(k0_prep, dim3(4), dim3(256), 0, stream,
                     W_l, b_l, W_r, b_r, W_qk, W_v, b_v, W_t, wsf);
  hipLaunchKernelGGL(k1_attn, dim3(N_ / 2), dim3(256), 0, stream,
                     x, y, wsf, b_t, stats);
  hipLaunchKernelGGL(k3_max, dim3(1024), dim3(256), 0, stream,
                     x, W_l, b_l, gamma, beta, tg, stats, pmax);
  hipLaunchKernelGGL(k4_final, dim3(64), dim3(64), 0, stream, pmax, out);
}